// Round 1
// baseline (428.204 us; speedup 1.0000x reference)
//
#include <hip/hip_runtime.h>
#include <hip/hip_fp16.h>

// Problem constants (from reference)
#define BATCH 2
#define SEQ 2048
#define EMB 1024
#define NH 16
#define HDIM 64
#define PROJ_IN 1024   // NH*HDIM

typedef _Float16 h16;
typedef __attribute__((ext_vector_type(8))) _Float16 h8;
typedef __attribute__((ext_vector_type(4))) _Float16 h4;
typedef __attribute__((ext_vector_type(4))) float f32x4;

#define MFMA16(a, b, c) __builtin_amdgcn_mfma_f32_16x16x32_f16((a), (b), (c), 0, 0, 0)

// ---------------------------------------------------------------------------
// Cast x [B*S][E] f32 -> f16, vectorized 4-wide
__global__ __launch_bounds__(256) void k_cast_x(const float* __restrict__ x,
                                                h16* __restrict__ xh) {
    int i = (blockIdx.x * 256 + threadIdx.x) * 4;
    float4 v = *(const float4*)(x + i);
    h4 o = { (h16)v.x, (h16)v.y, (h16)v.z, (h16)v.w };
    *(h4*)(xh + i) = o;
}

// W [NH][EMB][HDIM] f32 -> Wt [NH][HDIM][EMB] f16  (transpose for contiguous-K B-frags)
__global__ __launch_bounds__(256) void k_tr_w(const float* __restrict__ w,
                                              h16* __restrict__ wt) {
    int o = blockIdx.x * 256 + threadIdx.x;     // output index, coalesced write
    int e = o & (EMB - 1);
    int d = (o >> 10) & (HDIM - 1);
    int h = o >> 16;
    wt[o] = (h16)w[((size_t)h * EMB + e) * HDIM + d];
}

// Wproj [PROJ_IN][EMB] f32 -> Wpt [EMB][PROJ_IN] f16
__global__ __launch_bounds__(256) void k_tr_wp(const float* __restrict__ w,
                                               h16* __restrict__ wt) {
    int o = blockIdx.x * 256 + threadIdx.x;
    int k = o & (PROJ_IN - 1);
    int n = o >> 10;
    wt[o] = (h16)w[(size_t)k * EMB + n];
}

// ---------------------------------------------------------------------------
// Fused QKV projection. Grid: [B*H * S/128]. Block: 256 (4 waves x 32 rows).
// A-fragments (x rows) reused across Q/K/V -> 24 MFMA per 2 A-loads + 12 B-loads.
// Q,K stored [B*H][S][D]; V stored transposed [B*H][D][S] (B-operand layout for PV).
__global__ __launch_bounds__(256) void k_qkv(
    const h16* __restrict__ xh, const h16* __restrict__ wqt,
    const h16* __restrict__ wkt, const h16* __restrict__ wvt,
    h16* __restrict__ Q, h16* __restrict__ Kk, h16* __restrict__ Vt) {
    int mt = blockIdx.x & 15;          // 16 row-tiles of 128 per (b,h)
    int bh = blockIdx.x >> 4;          // 0..31
    int b = bh >> 4;
    int h = bh & 15;
    int wave = threadIdx.x >> 6, lane = threadIdx.x & 63;
    int lr = lane & 15, lg = lane >> 4;
    int row0 = mt * 128 + wave * 32;

    const h16* xp = xh + ((size_t)(b * SEQ) + row0) * EMB;
    const h16* wq = wqt + (size_t)h * HDIM * EMB;
    const h16* wk = wkt + (size_t)h * HDIM * EMB;
    const h16* wv = wvt + (size_t)h * HDIM * EMB;

    f32x4 aq[2][4], ak[2][4], av[2][4];
    f32x4 z = {0.f, 0.f, 0.f, 0.f};
#pragma unroll
    for (int m = 0; m < 2; m++)
#pragma unroll
        for (int n = 0; n < 4; n++) { aq[m][n] = z; ak[m][n] = z; av[m][n] = z; }

    for (int k0 = 0; k0 < EMB; k0 += 32) {
        h8 a[2];
#pragma unroll
        for (int m = 0; m < 2; m++)
            a[m] = *(const h8*)(xp + (size_t)(m * 16 + lr) * EMB + k0 + lg * 8);
#pragma unroll
        for (int n = 0; n < 4; n++) {
            size_t wo = (size_t)(n * 16 + lr) * EMB + k0 + lg * 8;
            h8 bq = *(const h8*)(wq + wo);
            h8 bk = *(const h8*)(wk + wo);
            h8 bv = *(const h8*)(wv + wo);
#pragma unroll
            for (int m = 0; m < 2; m++) {
                aq[m][n] = MFMA16(a[m], bq, aq[m][n]);
                ak[m][n] = MFMA16(a[m], bk, ak[m][n]);
                av[m][n] = MFMA16(a[m], bv, av[m][n]);
            }
        }
    }

    size_t qbase = (size_t)bh * SEQ * HDIM;
    size_t vbase = (size_t)bh * HDIM * SEQ;
#pragma unroll
    for (int m = 0; m < 2; m++)
#pragma unroll
        for (int n = 0; n < 4; n++)
#pragma unroll
            for (int r = 0; r < 4; r++) {
                int row = row0 + m * 16 + lg * 4 + r;   // C/D: col=lane&15, row=lg*4+reg
                int d = n * 16 + lr;
                Q[qbase + (size_t)row * HDIM + d] = (h16)aq[m][n][r];
                Kk[qbase + (size_t)row * HDIM + d] = (h16)ak[m][n][r];
                Vt[vbase + (size_t)d * SEQ + row] = (h16)av[m][n][r];
            }
}

// ---------------------------------------------------------------------------
// Flash attention. Grid: [B*H * S/128]. Block 256: 4 waves, each owns 32 q-rows.
// Waves fully independent (per-wave LDS region, per-wave causal tile count) -> no barriers.
__global__ __launch_bounds__(256) void k_attn(
    const h16* __restrict__ Q, const h16* __restrict__ Kk,
    const h16* __restrict__ Vt, h16* __restrict__ att) {
    __shared__ h16 lp[4][32][72];   // P tile per wave, stride 72 halves = 144B (16B-aligned, no 16-way conflict)

    int qt = blockIdx.x & 15;
    int bh = blockIdx.x >> 4;
    int b = bh >> 4;
    int h = bh & 15;
    int wave = threadIdx.x >> 6, lane = threadIdx.x & 63;
    int lr = lane & 15, lg = lane >> 4;
    int q0 = qt * 128 + wave * 32;

    const h16* Qp = Q + (size_t)bh * SEQ * HDIM;
    const h16* Kp = Kk + (size_t)bh * SEQ * HDIM;
    const h16* Vp = Vt + (size_t)bh * HDIM * SEQ;

    // Hoist Q fragments (reused across all K-tiles): 2 m-frags x 2 k-chunks
    h8 qf[2][2];
#pragma unroll
    for (int m = 0; m < 2; m++)
#pragma unroll
        for (int kc = 0; kc < 2; kc++)
            qf[m][kc] = *(const h8*)(Qp + (size_t)(q0 + m * 16 + lr) * HDIM + kc * 32 + lg * 8);

    float mrow[2][4], lrow[2][4];
    f32x4 acc[2][4];
    f32x4 z = {0.f, 0.f, 0.f, 0.f};
#pragma unroll
    for (int m = 0; m < 2; m++)
#pragma unroll
        for (int r = 0; r < 4; r++) { mrow[m][r] = -INFINITY; lrow[m][r] = 0.f; }
#pragma unroll
    for (int m = 0; m < 2; m++)
#pragma unroll
        for (int n = 0; n < 4; n++) acc[m][n] = z;

    int nkt = (q0 >> 6) + 1;   // causal: tiles with ks0 <= q0+31
    for (int kt = 0; kt < nkt; ++kt) {
        int ks0 = kt * 64;
        // ---- S-tile = Q @ K^T : M=32 (2 frags), N=64 (4 frags), K=64 (2 chunks)
        f32x4 sc[2][4];
#pragma unroll
        for (int m = 0; m < 2; m++)
#pragma unroll
            for (int n = 0; n < 4; n++) sc[m][n] = z;
#pragma unroll
        for (int kc = 0; kc < 2; kc++) {
            h8 bf[4];
#pragma unroll
            for (int n = 0; n < 4; n++)
                bf[n] = *(const h8*)(Kp + (size_t)(ks0 + n * 16 + lr) * HDIM + kc * 32 + lg * 8);
#pragma unroll
            for (int m = 0; m < 2; m++)
#pragma unroll
                for (int n = 0; n < 4; n++)
                    sc[m][n] = MFMA16(qf[m][kc], bf[n], sc[m][n]);
        }
        // ---- scale + causal mask + online softmax
#pragma unroll
        for (int m = 0; m < 2; m++) {
            int qg = q0 + m * 16 + lg * 4;
#pragma unroll
            for (int r = 0; r < 4; r++) {
                float tm = -1e30f;
#pragma unroll
                for (int n = 0; n < 4; n++) {
                    float s = sc[m][n][r] * 0.125f;
                    int kg = ks0 + n * 16 + lr;
                    s = (kg > qg + r) ? -1e30f : s;
                    sc[m][n][r] = s;
                    tm = fmaxf(tm, s);
                }
                tm = fmaxf(tm, __shfl_xor(tm, 1));
                tm = fmaxf(tm, __shfl_xor(tm, 2));
                tm = fmaxf(tm, __shfl_xor(tm, 4));
                tm = fmaxf(tm, __shfl_xor(tm, 8));
                float mnew = fmaxf(mrow[m][r], tm);
                float corr = __expf(mrow[m][r] - mnew);
                float ts = 0.f;
#pragma unroll
                for (int n = 0; n < 4; n++) {
                    float pv = __expf(sc[m][n][r] - mnew);
                    sc[m][n][r] = pv;
                    ts += pv;
                }
                ts += __shfl_xor(ts, 1);
                ts += __shfl_xor(ts, 2);
                ts += __shfl_xor(ts, 4);
                ts += __shfl_xor(ts, 8);
                lrow[m][r] = lrow[m][r] * corr + ts;
                mrow[m][r] = mnew;
#pragma unroll
                for (int n = 0; n < 4; n++) acc[m][n][r] *= corr;
            }
        }
        // ---- P -> LDS (C-layout scatter), then read back in A-layout
#pragma unroll
        for (int m = 0; m < 2; m++)
#pragma unroll
            for (int n = 0; n < 4; n++)
#pragma unroll
                for (int r = 0; r < 4; r++)
                    lp[wave][m * 16 + lg * 4 + r][n * 16 + lr] = (h16)sc[m][n][r];
        // ---- O += P @ V
#pragma unroll
        for (int kc = 0; kc < 2; kc++) {
            h8 pa[2], vf[4];
#pragma unroll
            for (int m = 0; m < 2; m++)
                pa[m] = *(const h8*)&lp[wave][m * 16 + lr][kc * 32 + lg * 8];
#pragma unroll
            for (int n = 0; n < 4; n++)
                vf[n] = *(const h8*)(Vp + (size_t)(n * 16 + lr) * SEQ + ks0 + kc * 32 + lg * 8);
#pragma unroll
            for (int m = 0; m < 2; m++)
#pragma unroll
                for (int n = 0; n < 4; n++)
                    acc[m][n] = MFMA16(pa[m], vf[n], acc[m][n]);
        }
    }
    // ---- epilogue: normalize, write concat-head layout [B*S][H*D] f16
#pragma unroll
    for (int m = 0; m < 2; m++)
#pragma unroll
        for (int n = 0; n < 4; n++)
#pragma unroll
            for (int r = 0; r < 4; r++) {
                int row = q0 + m * 16 + lg * 4 + r;
                float o = acc[m][n][r] / lrow[m][r];
                att[((size_t)(b * SEQ + row)) * PROJ_IN + h * HDIM + n * 16 + lr] = (h16)o;
            }
}

// ---------------------------------------------------------------------------
// Output projection + bias. Grid: [ (4096/128) * (1024/64) ]. Block 256.
__global__ __launch_bounds__(256) void k_proj(
    const h16* __restrict__ att, const h16* __restrict__ wpt,
    const float* __restrict__ bias, float* __restrict__ out) {
    int nt = blockIdx.x & 15;
    int mt = blockIdx.x >> 4;
    int wave = threadIdx.x >> 6, lane = threadIdx.x & 63;
    int lr = lane & 15, lg = lane >> 4;
    int row0 = mt * 128 + wave * 32;
    int col0 = nt * 64;

    f32x4 acc[2][4];
    f32x4 z = {0.f, 0.f, 0.f, 0.f};
#pragma unroll
    for (int m = 0; m < 2; m++)
#pragma unroll
        for (int n = 0; n < 4; n++) acc[m][n] = z;

    for (int k0 = 0; k0 < PROJ_IN; k0 += 32) {
        h8 a[2];
#pragma unroll
        for (int m = 0; m < 2; m++)
            a[m] = *(const h8*)(att + (size_t)(row0 + m * 16 + lr) * PROJ_IN + k0 + lg * 8);
        h8 bf[4];
#pragma unroll
        for (int n = 0; n < 4; n++)
            bf[n] = *(const h8*)(wpt + (size_t)(col0 + n * 16 + lr) * PROJ_IN + k0 + lg * 8);
#pragma unroll
        for (int m = 0; m < 2; m++)
#pragma unroll
            for (int n = 0; n < 4; n++)
                acc[m][n] = MFMA16(a[m], bf[n], acc[m][n]);
    }
#pragma unroll
    for (int m = 0; m < 2; m++)
#pragma unroll
        for (int n = 0; n < 4; n++)
#pragma unroll
            for (int r = 0; r < 4; r++) {
                int row = row0 + m * 16 + lg * 4 + r;
                int col = col0 + n * 16 + lr;
                out[(size_t)row * EMB + col] = acc[m][n][r] + bias[col];
            }
}

// ---------------------------------------------------------------------------
extern "C" void kernel_launch(void* const* d_in, const int* in_sizes, int n_in,
                              void* d_out, int out_size, void* d_ws, size_t ws_size,
                              hipStream_t stream) {
    const float* x = (const float*)d_in[0];
    const float* Wq = (const float*)d_in[1];
    const float* Wk = (const float*)d_in[2];
    const float* Wv = (const float*)d_in[3];
    const float* Wp = (const float*)d_in[4];
    const float* bp = (const float*)d_in[5];
    float* out = (float*)d_out;

    // Workspace carve-up (~40 MB total)
    char* p = (char*)d_ws;
    h16* xh = (h16*)p;  p += (size_t)BATCH * SEQ * EMB * 2;         // 8 MB
    h16* wqt = (h16*)p; p += (size_t)NH * HDIM * EMB * 2;           // 2 MB
    h16* wkt = (h16*)p; p += (size_t)NH * HDIM * EMB * 2;
    h16* wvt = (h16*)p; p += (size_t)NH * HDIM * EMB * 2;
    h16* wpt = (h16*)p; p += (size_t)EMB * PROJ_IN * 2;             // 2 MB
    h16* Qb = (h16*)p;  p += (size_t)BATCH * NH * SEQ * HDIM * 2;   // 8 MB
    h16* Kb = (h16*)p;  p += (size_t)BATCH * NH * SEQ * HDIM * 2;
    h16* Vb = (h16*)p;  p += (size_t)BATCH * NH * SEQ * HDIM * 2;
    h16* attb = (h16*)p;                                            // 8 MB

    k_cast_x<<<(BATCH * SEQ * EMB) / 4 / 256, 256, 0, stream>>>(x, xh);
    k_tr_w<<<(NH * EMB * HDIM) / 256, 256, 0, stream>>>(Wq, wqt);
    k_tr_w<<<(NH * EMB * HDIM) / 256, 256, 0, stream>>>(Wk, wkt);
    k_tr_w<<<(NH * EMB * HDIM) / 256, 256, 0, stream>>>(Wv, wvt);
    k_tr_wp<<<(EMB * PROJ_IN) / 256, 256, 0, stream>>>(Wp, wpt);
    k_qkv<<<BATCH * NH * (SEQ / 128), 256, 0, stream>>>(xh, wqt, wkt, wvt, Qb, Kb, Vb);
    k_attn<<<BATCH * NH * (SEQ / 128), 256, 0, stream>>>(Qb, Kb, Vb, attb);
    k_proj<<<(BATCH * SEQ / 128) * (EMB / 64), 256, 0, stream>>>(attb, wpt, bp, out);
}

// Round 2
// 360.844 us; speedup vs baseline: 1.1867x; 1.1867x over previous
//
#include <hip/hip_runtime.h>
#include <hip/hip_fp16.h>

#define BATCH 2
#define SEQ 2048
#define EMB 1024
#define NH 16
#define HDIM 64

typedef _Float16 h16;
typedef __attribute__((ext_vector_type(8))) _Float16 h8;
typedef __attribute__((ext_vector_type(4))) _Float16 h4;
typedef __attribute__((ext_vector_type(4))) float f32x4;

#define MFMA16(a, b, c) __builtin_amdgcn_mfma_f32_16x16x32_f16((a), (b), (c), 0, 0, 0)

// ---------------------------------------------------------------------------
// x [B*S][E] f32 -> f16
__global__ __launch_bounds__(256) void k_cast_x(const float* __restrict__ x,
                                                h16* __restrict__ xh) {
    int i = (blockIdx.x * 256 + threadIdx.x) * 4;
    float4 v = *(const float4*)(x + i);
    h4 o = { (h16)v.x, (h16)v.y, (h16)v.z, (h16)v.w };
    *(h4*)(xh + i) = o;
}

// Wq/Wk/Wv [NH][EMB][HDIM] f32 -> wcat[(h*3+mat)*64+d][EMB] f16 (n-major, k-contig)
__global__ __launch_bounds__(256) void k_tr_qkv3(const float* __restrict__ wq,
                                                 const float* __restrict__ wk,
                                                 const float* __restrict__ wv,
                                                 h16* __restrict__ wcat) {
    int o = blockIdx.x * 256 + threadIdx.x;       // [0, 3M)
    int mat = o >> 20;
    int w = o & ((1 << 20) - 1);
    int e = w & 1023, d = (w >> 10) & 63, h = w >> 16;
    const float* src = (mat == 0) ? wq : (mat == 1) ? wk : wv;
    wcat[(((size_t)(h * 3 + mat) * 64 + d) << 10) | e] =
        (h16)src[((size_t)(h << 10) + e) * 64 + d];
}

// Wproj [PROJ_IN][EMB] f32 -> wpt [EMB_n][PROJ_IN_k] f16
__global__ __launch_bounds__(256) void k_tr_wp(const float* __restrict__ w,
                                               h16* __restrict__ wt) {
    int o = blockIdx.x * 256 + threadIdx.x;
    int k = o & 1023, n = o >> 10;
    wt[o] = (h16)w[((size_t)k << 10) | n];
}

// ---------------------------------------------------------------------------
// Shared GEMM core: one wave computes a 32x64 tile, K=1024, A/B row-major k-contig.
__device__ __forceinline__ void gemm_tile(const h16* __restrict__ ap,
                                          const h16* __restrict__ bp,
                                          int lr, int lg, f32x4 acc[2][4]) {
#pragma unroll 2
    for (int k0 = 0; k0 < 1024; k0 += 32) {
        h8 a[2], b[4];
#pragma unroll
        for (int m = 0; m < 2; m++)
            a[m] = *(const h8*)(ap + (size_t)(m * 16 + lr) * 1024 + k0 + lg * 8);
#pragma unroll
        for (int n = 0; n < 4; n++)
            b[n] = *(const h8*)(bp + (size_t)(n * 16 + lr) * 1024 + k0 + lg * 8);
#pragma unroll
        for (int m = 0; m < 2; m++)
#pragma unroll
            for (int n = 0; n < 4; n++)
                acc[m][n] = MFMA16(a[m], b[n], acc[m][n]);
    }
}

// Fused QKV: x[4096][1024] @ wcat^T -> per-(h,mat) 64-col tiles.
// Grid: 32 mt * 48 nt = 1536 blocks (24 waves/CU).
__global__ __launch_bounds__(256) void k_qkv(
    const h16* __restrict__ xh, const h16* __restrict__ wcat,
    h16* __restrict__ Q, h16* __restrict__ Kk, h16* __restrict__ Vt) {
    int bid = blockIdx.x;
    int nt = bid % 48, mt = bid / 48;
    int wave = threadIdx.x >> 6, lane = threadIdx.x & 63;
    int lr = lane & 15, lg = lane >> 4;
    int row0 = mt * 128 + wave * 32;

    f32x4 acc[2][4];
#pragma unroll
    for (int m = 0; m < 2; m++)
#pragma unroll
        for (int n = 0; n < 4; n++) acc[m][n] = (f32x4){0.f, 0.f, 0.f, 0.f};

    gemm_tile(xh + (size_t)row0 * 1024, wcat + (size_t)nt * 64 * 1024, lr, lg, acc);

    int h = nt / 3, mat = nt - h * 3;
    if (mat == 2) {
        // V^T[bh][d][s]: 4 acc regs = 4 consecutive s -> packed 8B store
#pragma unroll
        for (int m = 0; m < 2; m++)
#pragma unroll
            for (int n = 0; n < 4; n++) {
                int row = row0 + m * 16 + lg * 4;
                int b = row >> 11, s = row & 2047;
                int bh = b * 16 + h;
                int d = n * 16 + lr;
                h4 o = { (h16)acc[m][n][0], (h16)acc[m][n][1],
                         (h16)acc[m][n][2], (h16)acc[m][n][3] };
                *(h4*)&Vt[((size_t)bh * 64 + d) * 2048 + s] = o;
            }
    } else {
        h16* dst = (mat == 0) ? Q : Kk;
#pragma unroll
        for (int m = 0; m < 2; m++)
#pragma unroll
            for (int n = 0; n < 4; n++)
#pragma unroll
                for (int r = 0; r < 4; r++) {
                    int row = row0 + m * 16 + lg * 4 + r;
                    int bh = (row >> 11) * 16 + h, s = row & 2047;
                    dst[((size_t)bh * 2048 + s) * 64 + n * 16 + lr] = (h16)acc[m][n][r];
                }
    }
}

// Output projection + bias. Grid 512 blocks.
__global__ __launch_bounds__(256) void k_proj(
    const h16* __restrict__ att, const h16* __restrict__ wpt,
    const float* __restrict__ bias, float* __restrict__ out) {
    int nt = blockIdx.x & 15, mt = blockIdx.x >> 4;
    int wave = threadIdx.x >> 6, lane = threadIdx.x & 63;
    int lr = lane & 15, lg = lane >> 4;
    int row0 = mt * 128 + wave * 32;
    int col0 = nt * 64;

    f32x4 acc[2][4];
#pragma unroll
    for (int m = 0; m < 2; m++)
#pragma unroll
        for (int n = 0; n < 4; n++) acc[m][n] = (f32x4){0.f, 0.f, 0.f, 0.f};

    gemm_tile(att + (size_t)row0 * 1024, wpt + (size_t)col0 * 1024, lr, lg, acc);

#pragma unroll
    for (int m = 0; m < 2; m++)
#pragma unroll
        for (int n = 0; n < 4; n++)
#pragma unroll
            for (int r = 0; r < 4; r++) {
                int row = row0 + m * 16 + lg * 4 + r;
                int col = col0 + n * 16 + lr;
                out[(size_t)row * 1024 + col] = acc[m][n][r] + bias[col];
            }
}

// ---------------------------------------------------------------------------
// Transposed flash attention.
// Wave computes S^T = mfma(K, Q): lane holds P-columns for 2 q-rows ->
// in-lane softmax (2 shfls/qf), packed b64 P writes, O^T = mfma(V^T, P),
// in-lane rescale + epilogue. Defer-max (m0=0, THR=8). No barriers.
// Causal load balance: wave w of block g -> q-chunks {g, 31-g, 32+g, 63-g}
// (each block = exactly 66 tile-units).
__global__ __launch_bounds__(256) void k_attn(
    const h16* __restrict__ Q, const h16* __restrict__ Kk,
    const h16* __restrict__ Vt, h16* __restrict__ att) {
    __shared__ h16 lp[4][32][72];   // per-wave P tile [q_local][k], stride 144B

    int g = blockIdx.x & 15;
    int bh = blockIdx.x >> 4;
    int b = bh >> 4, h = bh & 15;
    int wave = threadIdx.x >> 6, lane = threadIdx.x & 63;
    int lr = lane & 15, lg = lane >> 4;
    int c = (wave == 0) ? g : (wave == 1) ? 31 - g : (wave == 2) ? 32 + g : 63 - g;
    int q0 = c * 32;

    const h16* Qp = Q + (size_t)bh * SEQ * HDIM;
    const h16* Kp = Kk + (size_t)bh * SEQ * HDIM;
    const h16* Vp = Vt + (size_t)bh * HDIM * SEQ;

    // Q as B-operand: col=q, k-dim=d
    h8 qb[2][2];
#pragma unroll
    for (int qf = 0; qf < 2; qf++)
#pragma unroll
        for (int dc = 0; dc < 2; dc++)
            qb[qf][dc] = *(const h8*)(Qp + (size_t)(q0 + qf * 16 + lr) * 64 + dc * 32 + lg * 8);

    const float SC = 0.125f * 1.44269504f;   // scale folded into exp2 domain
    float mx[2] = {0.f, 0.f}, lsum[2] = {0.f, 0.f};
    f32x4 ot[4][2];   // O^T acc: [df][qf], row=d, col=q
#pragma unroll
    for (int df = 0; df < 4; df++)
#pragma unroll
        for (int qf = 0; qf < 2; qf++) ot[df][qf] = (f32x4){0.f, 0.f, 0.f, 0.f};

    int nkt = (q0 >> 6) + 1;
    for (int kt = 0; kt < nkt; ++kt) {
        int ks0 = kt << 6;
        // ---- S^T = K @ Q^T : rows=k (4 frags), cols=q (2 frags)
        f32x4 st[4][2];
#pragma unroll
        for (int kf = 0; kf < 4; kf++)
#pragma unroll
            for (int qf = 0; qf < 2; qf++) st[kf][qf] = (f32x4){0.f, 0.f, 0.f, 0.f};
#pragma unroll
        for (int dc = 0; dc < 2; dc++) {
            h8 ka[4];
#pragma unroll
            for (int kf = 0; kf < 4; kf++)
                ka[kf] = *(const h8*)(Kp + (size_t)(ks0 + kf * 16 + lr) * 64 + dc * 32 + lg * 8);
#pragma unroll
            for (int kf = 0; kf < 4; kf++)
#pragma unroll
                for (int qf = 0; qf < 2; qf++)
                    st[kf][qf] = MFMA16(ka[kf], qb[qf][dc], st[kf][qf]);
        }
        // ---- prefetch V frags (independent of softmax; hides L2 latency)
        h8 va[2][4];
#pragma unroll
        for (int kc = 0; kc < 2; kc++)
#pragma unroll
            for (int df = 0; df < 4; df++)
                va[kc][df] = *(const h8*)(Vp + (size_t)(df * 16 + lr) * 2048 + ks0 + kc * 32 + lg * 8);

        // ---- scale (+ causal mask, last tile only: wave-uniform branch)
        if (ks0 + 64 > q0) {
#pragma unroll
            for (int kf = 0; kf < 4; kf++)
#pragma unroll
                for (int qf = 0; qf < 2; qf++)
#pragma unroll
                    for (int r = 0; r < 4; r++) {
                        int kg = ks0 + kf * 16 + lg * 4 + r;
                        int qg = q0 + qf * 16 + lr;
                        float s = st[kf][qf][r] * SC;
                        st[kf][qf][r] = (kg > qg) ? -1e30f : s;
                    }
        } else {
#pragma unroll
            for (int kf = 0; kf < 4; kf++)
#pragma unroll
                for (int qf = 0; qf < 2; qf++)
#pragma unroll
                    for (int r = 0; r < 4; r++)
                        st[kf][qf][r] *= SC;
        }
        // ---- per-q tile max: in-lane 16 + 2 shfls across lg
        float tm[2];
#pragma unroll
        for (int qf = 0; qf < 2; qf++) {
            float t = st[0][qf][0];
#pragma unroll
            for (int kf = 0; kf < 4; kf++)
#pragma unroll
                for (int r = 0; r < 4; r++) t = fmaxf(t, st[kf][qf][r]);
            t = fmaxf(t, __shfl_xor(t, 16));
            t = fmaxf(t, __shfl_xor(t, 32));
            tm[qf] = t;
        }
        // ---- defer-max: rescale only if tile max grew past THR=8
        if (__any((tm[0] > mx[0] + 8.f) || (tm[1] > mx[1] + 8.f))) {
#pragma unroll
            for (int qf = 0; qf < 2; qf++) {
                float mn = fmaxf(mx[qf], tm[qf]);
                float corr = exp2f(mx[qf] - mn);
                lsum[qf] *= corr;
#pragma unroll
                for (int df = 0; df < 4; df++) ot[df][qf] *= corr;
                mx[qf] = mn;
            }
        }
        // ---- P = exp2(t - m), pack 4 consecutive k -> one b64 LDS write
        float ts[2] = {0.f, 0.f};
#pragma unroll
        for (int kf = 0; kf < 4; kf++)
#pragma unroll
            for (int qf = 0; qf < 2; qf++) {
                float p0 = exp2f(st[kf][qf][0] - mx[qf]);
                float p1 = exp2f(st[kf][qf][1] - mx[qf]);
                float p2 = exp2f(st[kf][qf][2] - mx[qf]);
                float p3 = exp2f(st[kf][qf][3] - mx[qf]);
                ts[qf] += (p0 + p1) + (p2 + p3);
                h4 ph = { (h16)p0, (h16)p1, (h16)p2, (h16)p3 };
                *(h4*)&lp[wave][qf * 16 + lr][kf * 16 + lg * 4] = ph;
            }
#pragma unroll
        for (int qf = 0; qf < 2; qf++) {
            float t = ts[qf];
            t += __shfl_xor(t, 16);
            t += __shfl_xor(t, 32);
            lsum[qf] += t;
        }
        // ---- O^T += V^T @ P^T
#pragma unroll
        for (int kc = 0; kc < 2; kc++) {
            h8 pb[2];
#pragma unroll
            for (int qf = 0; qf < 2; qf++)
                pb[qf] = *(const h8*)&lp[wave][qf * 16 + lr][kc * 32 + lg * 8];
#pragma unroll
            for (int df = 0; df < 4; df++)
#pragma unroll
                for (int qf = 0; qf < 2; qf++)
                    ot[df][qf] = MFMA16(va[kc][df], pb[qf], ot[df][qf]);
        }
    }
    // ---- epilogue: O^T/l -> att[b*S+q][h*64+d], 4 consecutive d packed
#pragma unroll
    for (int qf = 0; qf < 2; qf++) {
        float rl = 1.f / lsum[qf];
        int q = q0 + qf * 16 + lr;
#pragma unroll
        for (int df = 0; df < 4; df++) {
            h4 o = { (h16)(ot[df][qf][0] * rl), (h16)(ot[df][qf][1] * rl),
                     (h16)(ot[df][qf][2] * rl), (h16)(ot[df][qf][3] * rl) };
            *(h4*)&att[((size_t)(b * SEQ + q)) * 1024 + h * 64 + df * 16 + lg * 4] = o;
        }
    }
}

// ---------------------------------------------------------------------------
extern "C" void kernel_launch(void* const* d_in, const int* in_sizes, int n_in,
                              void* d_out, int out_size, void* d_ws, size_t ws_size,
                              hipStream_t stream) {
    const float* x = (const float*)d_in[0];
    const float* Wq = (const float*)d_in[1];
    const float* Wk = (const float*)d_in[2];
    const float* Wv = (const float*)d_in[3];
    const float* Wp = (const float*)d_in[4];
    const float* bp = (const float*)d_in[5];
    float* out = (float*)d_out;

    char* p = (char*)d_ws;
    h16* xh = (h16*)p;   p += (size_t)BATCH * SEQ * EMB * 2;          // 8 MB
    h16* wcat = (h16*)p; p += (size_t)NH * 3 * HDIM * EMB * 2;        // 6 MB
    h16* wpt = (h16*)p;  p += (size_t)EMB * EMB * 2;                  // 2 MB
    h16* Qb = (h16*)p;   p += (size_t)BATCH * NH * SEQ * HDIM * 2;    // 8 MB
    h16* Kb = (h16*)p;   p += (size_t)BATCH * NH * SEQ * HDIM * 2;
    h16* Vb = (h16*)p;   p += (size_t)BATCH * NH * SEQ * HDIM * 2;
    h16* attb = (h16*)p;                                              // 8 MB

    k_cast_x<<<(BATCH * SEQ * EMB) / 4 / 256, 256, 0, stream>>>(x, xh);
    k_tr_qkv3<<<3 * NH * EMB * HDIM / 256, 256, 0, stream>>>(Wq, Wk, Wv, wcat);
    k_tr_wp<<<EMB * EMB / 256, 256, 0, stream>>>(Wp, wpt);
    k_qkv<<<32 * 48, 256, 0, stream>>>(xh, wcat, Qb, Kb, Vb);
    k_attn<<<BATCH * NH * 16, 256, 0, stream>>>(Qb, Kb, Vb, attb);
    k_proj<<<32 * 16, 256, 0, stream>>>(attb, wpt, bp, out);
}

// Round 3
// 239.223 us; speedup vs baseline: 1.7900x; 1.5084x over previous
//
#include <hip/hip_runtime.h>
#include <hip/hip_fp16.h>

#define BATCH 2
#define SEQ 2048
#define EMB 1024
#define NH 16
#define HDIM 64

typedef _Float16 h16;
typedef __attribute__((ext_vector_type(8))) _Float16 h8;
typedef __attribute__((ext_vector_type(4))) _Float16 h4;
typedef __attribute__((ext_vector_type(4))) float f32x4;

#define MFMA16(a, b, c) __builtin_amdgcn_mfma_f32_16x16x32_f16((a), (b), (c), 0, 0, 0)

// async global->LDS, 16B per lane. LDS dest is wave-uniform base + lane*16.
__device__ __forceinline__ void g2l16(const void* g, void* l) {
    __builtin_amdgcn_global_load_lds(
        (const __attribute__((address_space(1))) unsigned int*)g,
        (__attribute__((address_space(3))) unsigned int*)l, 16, 0, 0);
}

// ---------------------------------------------------------------------------
// x [B*S][E] f32 -> f16
__global__ __launch_bounds__(256) void k_cast_x(const float* __restrict__ x,
                                                h16* __restrict__ xh) {
    int i = (blockIdx.x * 256 + threadIdx.x) * 4;
    float4 v = *(const float4*)(x + i);
    h4 o = { (h16)v.x, (h16)v.y, (h16)v.z, (h16)v.w };
    *(h4*)(xh + i) = o;
}

// Wq/Wk/Wv [NH][EMB][HDIM] f32 -> wcat[(h*3+mat)*64+d][EMB] f16 (n-major, k-contig)
__global__ __launch_bounds__(256) void k_tr_qkv3(const float* __restrict__ wq,
                                                 const float* __restrict__ wk,
                                                 const float* __restrict__ wv,
                                                 h16* __restrict__ wcat) {
    int o = blockIdx.x * 256 + threadIdx.x;       // [0, 3M)
    int mat = o >> 20;
    int w = o & ((1 << 20) - 1);
    int e = w & 1023, d = (w >> 10) & 63, h = w >> 16;
    const float* src = (mat == 0) ? wq : (mat == 1) ? wk : wv;
    wcat[(((size_t)(h * 3 + mat) * 64 + d) << 10) | e] =
        (h16)src[((size_t)(h << 10) + e) * 64 + d];
}

// Wproj [PROJ_IN][EMB] f32 -> wpt [EMB_n][PROJ_IN_k] f16
__global__ __launch_bounds__(256) void k_tr_wp(const float* __restrict__ w,
                                               h16* __restrict__ wt) {
    int o = blockIdx.x * 256 + threadIdx.x;
    int k = o & 1023, n = o >> 10;
    wt[o] = (h16)w[((size_t)k << 10) | n];
}

// ---------------------------------------------------------------------------
// m97-structure QKV GEMM: M=4096, N=3072, K=1024. 128x128 tile, BK=32.
// 4 waves in 2x2, each computes a 64x64 quadrant (4x4 16x16 frags).
// LDS staged via global_load_lds w=16; 16B-granule XOR swizzle (rule #21:
// linear LDS dest + inverse-swizzled global SOURCE + swizzled ds_read).
__global__ __launch_bounds__(256) void k_qkv(
    const h16* __restrict__ xh, const h16* __restrict__ wcat,
    h16* __restrict__ Q, h16* __restrict__ Kk, h16* __restrict__ Vt) {
    __shared__ h16 As[128 * 32];
    __shared__ h16 Bs[128 * 32];
    int tid = threadIdx.x;
    int wave = tid >> 6, lane = tid & 63;
    int lr = lane & 15, lg = lane >> 4;
    int wr = wave >> 1, wc = wave & 1;
    int nt = blockIdx.x % 24, mt = blockIdx.x / 24;

    const char* Ab = (const char*)xh + (size_t)mt * 128 * 2048;
    const char* Bb = (const char*)wcat + (size_t)nt * 128 * 2048;
    int srow = tid >> 2;                                   // 0..63
    int scolb = (((tid & 3) ^ (srow & 3))) * 16;           // swizzled source granule
    const char* As0 = Ab + (size_t)srow * 2048 + scolb;
    const char* Bs0 = Bb + (size_t)srow * 2048 + scolb;
    h16* AsW = As + wave * 512;                            // per-wave 1KB staging base
    h16* BsW = Bs + wave * 512;

    f32x4 acc[4][4];
#pragma unroll
    for (int m = 0; m < 4; m++)
#pragma unroll
        for (int n = 0; n < 4; n++) acc[m][n] = (f32x4){0.f, 0.f, 0.f, 0.f};

    for (int k0 = 0; k0 < 1024; k0 += 32) {
        size_t kb = (size_t)k0 * 2;
        g2l16(As0 + kb, AsW);
        g2l16(As0 + 64 * 2048 + kb, AsW + 2048);
        g2l16(Bs0 + kb, BsW);
        g2l16(Bs0 + 64 * 2048 + kb, BsW + 2048);
        __syncthreads();
        h8 a[4], b[4];
#pragma unroll
        for (int m = 0; m < 4; m++)
            a[m] = *(const h8*)&As[(wr * 64 + m * 16 + lr) * 32 + (lg ^ (lr & 3)) * 8];
#pragma unroll
        for (int n = 0; n < 4; n++)
            b[n] = *(const h8*)&Bs[(wc * 64 + n * 16 + lr) * 32 + (lg ^ (lr & 3)) * 8];
#pragma unroll
        for (int m = 0; m < 4; m++)
#pragma unroll
            for (int n = 0; n < 4; n++)
                acc[m][n] = MFMA16(a[m], b[n], acc[m][n]);
        __syncthreads();
    }

    // epilogue: group g (64 output cols) is wave-uniform
    int g = nt * 2 + wc;
    int mat = g % 3, hh = g / 3;
    int row0 = mt * 128 + wr * 64;
    if (mat == 2) {
#pragma unroll
        for (int m = 0; m < 4; m++)
#pragma unroll
            for (int n = 0; n < 4; n++) {
                int row = row0 + m * 16 + lg * 4;
                int b = row >> 11, s = row & 2047;
                int bh = b * 16 + hh;
                int d = n * 16 + lr;
                h4 o = { (h16)acc[m][n][0], (h16)acc[m][n][1],
                         (h16)acc[m][n][2], (h16)acc[m][n][3] };
                *(h4*)&Vt[((size_t)bh * 64 + d) * 2048 + s] = o;
            }
    } else {
        h16* dst = mat ? Kk : Q;
#pragma unroll
        for (int m = 0; m < 4; m++)
#pragma unroll
            for (int n = 0; n < 4; n++)
#pragma unroll
                for (int r = 0; r < 4; r++) {
                    int row = row0 + m * 16 + lg * 4 + r;
                    int bh = (row >> 11) * 16 + hh, s = row & 2047;
                    dst[((size_t)bh * 2048 + s) * 64 + n * 16 + lr] = (h16)acc[m][n][r];
                }
    }
}

// ---------------------------------------------------------------------------
// m97-structure out-projection: M=4096, N=1024, K=1024. 128x64 tile, BK=32.
// 4 waves stacked on M (each 32x64, 2x4 frags). Grid 512 blocks.
__global__ __launch_bounds__(256) void k_proj(
    const h16* __restrict__ att, const h16* __restrict__ wpt,
    const float* __restrict__ bias, float* __restrict__ out) {
    __shared__ h16 As[128 * 32];
    __shared__ h16 Bs[64 * 32];
    int tid = threadIdx.x;
    int wave = tid >> 6, lane = tid & 63;
    int lr = lane & 15, lg = lane >> 4;
    int nt = blockIdx.x & 15, mt = blockIdx.x >> 4;

    const char* Ab = (const char*)att + (size_t)mt * 128 * 2048;
    const char* Bb = (const char*)wpt + (size_t)nt * 64 * 2048;
    int srow = tid >> 2;
    int scolb = (((tid & 3) ^ (srow & 3))) * 16;
    const char* As0 = Ab + (size_t)srow * 2048 + scolb;
    const char* Bs0 = Bb + (size_t)srow * 2048 + scolb;
    h16* AsW = As + wave * 512;
    h16* BsW = Bs + wave * 512;

    f32x4 acc[2][4];
#pragma unroll
    for (int m = 0; m < 2; m++)
#pragma unroll
        for (int n = 0; n < 4; n++) acc[m][n] = (f32x4){0.f, 0.f, 0.f, 0.f};

    for (int k0 = 0; k0 < 1024; k0 += 32) {
        size_t kb = (size_t)k0 * 2;
        g2l16(As0 + kb, AsW);
        g2l16(As0 + 64 * 2048 + kb, AsW + 2048);
        g2l16(Bs0 + kb, BsW);                       // B tile 4KB: one call
        __syncthreads();
        h8 a[2], b[4];
#pragma unroll
        for (int m = 0; m < 2; m++)
            a[m] = *(const h8*)&As[(wave * 32 + m * 16 + lr) * 32 + (lg ^ (lr & 3)) * 8];
#pragma unroll
        for (int n = 0; n < 4; n++)
            b[n] = *(const h8*)&Bs[(n * 16 + lr) * 32 + (lg ^ (lr & 3)) * 8];
#pragma unroll
        for (int m = 0; m < 2; m++)
#pragma unroll
            for (int n = 0; n < 4; n++)
                acc[m][n] = MFMA16(a[m], b[n], acc[m][n]);
        __syncthreads();
    }

#pragma unroll
    for (int m = 0; m < 2; m++)
#pragma unroll
        for (int n = 0; n < 4; n++)
#pragma unroll
            for (int r = 0; r < 4; r++) {
                int row = mt * 128 + wave * 32 + m * 16 + lg * 4 + r;
                int col = nt * 64 + n * 16 + lr;
                out[(size_t)row * 1024 + col] = acc[m][n][r] + bias[col];
            }
}

// ---------------------------------------------------------------------------
// Transposed flash attention (unchanged from round 1 — passing, ~balanced).
__global__ __launch_bounds__(256) void k_attn(
    const h16* __restrict__ Q, const h16* __restrict__ Kk,
    const h16* __restrict__ Vt, h16* __restrict__ att) {
    __shared__ h16 lp[4][32][72];

    int g = blockIdx.x & 15;
    int bh = blockIdx.x >> 4;
    int b = bh >> 4, h = bh & 15;
    int wave = threadIdx.x >> 6, lane = threadIdx.x & 63;
    int lr = lane & 15, lg = lane >> 4;
    int c = (wave == 0) ? g : (wave == 1) ? 31 - g : (wave == 2) ? 32 + g : 63 - g;
    int q0 = c * 32;

    const h16* Qp = Q + (size_t)bh * SEQ * HDIM;
    const h16* Kp = Kk + (size_t)bh * SEQ * HDIM;
    const h16* Vp = Vt + (size_t)bh * HDIM * SEQ;

    h8 qb[2][2];
#pragma unroll
    for (int qf = 0; qf < 2; qf++)
#pragma unroll
        for (int dc = 0; dc < 2; dc++)
            qb[qf][dc] = *(const h8*)(Qp + (size_t)(q0 + qf * 16 + lr) * 64 + dc * 32 + lg * 8);

    const float SC = 0.125f * 1.44269504f;
    float mx[2] = {0.f, 0.f}, lsum[2] = {0.f, 0.f};
    f32x4 ot[4][2];
#pragma unroll
    for (int df = 0; df < 4; df++)
#pragma unroll
        for (int qf = 0; qf < 2; qf++) ot[df][qf] = (f32x4){0.f, 0.f, 0.f, 0.f};

    int nkt = (q0 >> 6) + 1;
    for (int kt = 0; kt < nkt; ++kt) {
        int ks0 = kt << 6;
        f32x4 st[4][2];
#pragma unroll
        for (int kf = 0; kf < 4; kf++)
#pragma unroll
            for (int qf = 0; qf < 2; qf++) st[kf][qf] = (f32x4){0.f, 0.f, 0.f, 0.f};
#pragma unroll
        for (int dc = 0; dc < 2; dc++) {
            h8 ka[4];
#pragma unroll
            for (int kf = 0; kf < 4; kf++)
                ka[kf] = *(const h8*)(Kp + (size_t)(ks0 + kf * 16 + lr) * 64 + dc * 32 + lg * 8);
#pragma unroll
            for (int kf = 0; kf < 4; kf++)
#pragma unroll
                for (int qf = 0; qf < 2; qf++)
                    st[kf][qf] = MFMA16(ka[kf], qb[qf][dc], st[kf][qf]);
        }
        h8 va[2][4];
#pragma unroll
        for (int kc = 0; kc < 2; kc++)
#pragma unroll
            for (int df = 0; df < 4; df++)
                va[kc][df] = *(const h8*)(Vp + (size_t)(df * 16 + lr) * 2048 + ks0 + kc * 32 + lg * 8);

        if (ks0 + 64 > q0) {
#pragma unroll
            for (int kf = 0; kf < 4; kf++)
#pragma unroll
                for (int qf = 0; qf < 2; qf++)
#pragma unroll
                    for (int r = 0; r < 4; r++) {
                        int kg = ks0 + kf * 16 + lg * 4 + r;
                        int qg = q0 + qf * 16 + lr;
                        float s = st[kf][qf][r] * SC;
                        st[kf][qf][r] = (kg > qg) ? -1e30f : s;
                    }
        } else {
#pragma unroll
            for (int kf = 0; kf < 4; kf++)
#pragma unroll
                for (int qf = 0; qf < 2; qf++)
#pragma unroll
                    for (int r = 0; r < 4; r++)
                        st[kf][qf][r] *= SC;
        }
        float tm[2];
#pragma unroll
        for (int qf = 0; qf < 2; qf++) {
            float t = st[0][qf][0];
#pragma unroll
            for (int kf = 0; kf < 4; kf++)
#pragma unroll
                for (int r = 0; r < 4; r++) t = fmaxf(t, st[kf][qf][r]);
            t = fmaxf(t, __shfl_xor(t, 16));
            t = fmaxf(t, __shfl_xor(t, 32));
            tm[qf] = t;
        }
        if (__any((tm[0] > mx[0] + 8.f) || (tm[1] > mx[1] + 8.f))) {
#pragma unroll
            for (int qf = 0; qf < 2; qf++) {
                float mn = fmaxf(mx[qf], tm[qf]);
                float corr = exp2f(mx[qf] - mn);
                lsum[qf] *= corr;
#pragma unroll
                for (int df = 0; df < 4; df++) ot[df][qf] *= corr;
                mx[qf] = mn;
            }
        }
        float ts[2] = {0.f, 0.f};
#pragma unroll
        for (int kf = 0; kf < 4; kf++)
#pragma unroll
            for (int qf = 0; qf < 2; qf++) {
                float p0 = exp2f(st[kf][qf][0] - mx[qf]);
                float p1 = exp2f(st[kf][qf][1] - mx[qf]);
                float p2 = exp2f(st[kf][qf][2] - mx[qf]);
                float p3 = exp2f(st[kf][qf][3] - mx[qf]);
                ts[qf] += (p0 + p1) + (p2 + p3);
                h4 ph = { (h16)p0, (h16)p1, (h16)p2, (h16)p3 };
                *(h4*)&lp[wave][qf * 16 + lr][kf * 16 + lg * 4] = ph;
            }
#pragma unroll
        for (int qf = 0; qf < 2; qf++) {
            float t = ts[qf];
            t += __shfl_xor(t, 16);
            t += __shfl_xor(t, 32);
            lsum[qf] += t;
        }
#pragma unroll
        for (int kc = 0; kc < 2; kc++) {
            h8 pb[2];
#pragma unroll
            for (int qf = 0; qf < 2; qf++)
                pb[qf] = *(const h8*)&lp[wave][qf * 16 + lr][kc * 32 + lg * 8];
#pragma unroll
            for (int df = 0; df < 4; df++)
#pragma unroll
                for (int qf = 0; qf < 2; qf++)
                    ot[df][qf] = MFMA16(va[kc][df], pb[qf], ot[df][qf]);
        }
    }
#pragma unroll
    for (int qf = 0; qf < 2; qf++) {
        float rl = 1.f / lsum[qf];
        int q = q0 + qf * 16 + lr;
#pragma unroll
        for (int df = 0; df < 4; df++) {
            h4 o = { (h16)(ot[df][qf][0] * rl), (h16)(ot[df][qf][1] * rl),
                     (h16)(ot[df][qf][2] * rl), (h16)(ot[df][qf][3] * rl) };
            *(h4*)&att[((size_t)(b * SEQ + q)) * 1024 + h * 64 + df * 16 + lg * 4] = o;
        }
    }
}

// ---------------------------------------------------------------------------
extern "C" void kernel_launch(void* const* d_in, const int* in_sizes, int n_in,
                              void* d_out, int out_size, void* d_ws, size_t ws_size,
                              hipStream_t stream) {
    const float* x = (const float*)d_in[0];
    const float* Wq = (const float*)d_in[1];
    const float* Wk = (const float*)d_in[2];
    const float* Wv = (const float*)d_in[3];
    const float* Wp = (const float*)d_in[4];
    const float* bp = (const float*)d_in[5];
    float* out = (float*)d_out;

    char* p = (char*)d_ws;
    h16* xh = (h16*)p;   p += (size_t)BATCH * SEQ * EMB * 2;
    h16* wcat = (h16*)p; p += (size_t)NH * 3 * HDIM * EMB * 2;
    h16* wpt = (h16*)p;  p += (size_t)EMB * EMB * 2;
    h16* Qb = (h16*)p;   p += (size_t)BATCH * NH * SEQ * HDIM * 2;
    h16* Kb = (h16*)p;   p += (size_t)BATCH * NH * SEQ * HDIM * 2;
    h16* Vb = (h16*)p;   p += (size_t)BATCH * NH * SEQ * HDIM * 2;
    h16* attb = (h16*)p;

    k_cast_x<<<(BATCH * SEQ * EMB) / 4 / 256, 256, 0, stream>>>(x, xh);
    k_tr_qkv3<<<3 * NH * EMB * HDIM / 256, 256, 0, stream>>>(Wq, Wk, Wv, wcat);
    k_tr_wp<<<EMB * EMB / 256, 256, 0, stream>>>(Wp, wpt);
    k_qkv<<<32 * 24, 256, 0, stream>>>(xh, wcat, Qb, Kb, Vb);
    k_attn<<<BATCH * NH * 16, 256, 0, stream>>>(Qb, Kb, Vb, attb);
    k_proj<<<32 * 16, 256, 0, stream>>>(attb, wpt, bp, out);
}